// Round 2
// baseline (200.563 us; speedup 1.0000x reference)
//
#include <hip/hip_runtime.h>

#define NU 60082
#define NST 14695
#define D 128
#define B 8
#define K 32

// ws layout (floats):
//   [0..127]   v  = proj_w @ w_st
//   [128]      c  = proj_b . w_st
//   [136..143] uc[b] = user_out[b] + b_st
#define WS_V   0
#define WS_C   128
#define WS_UC  136

// One block per batch row b. Computes v/c/uc (block 0 + per-b uc -> ws) and
// writes the <=64 overridden out[b,n] entries directly (first-occurrence
// dedup, duplicates accumulate per JAX .add semantics).
__global__ __launch_bounds__(256) void k_patch(
    const float* __restrict__ user_embedding,
    const float* __restrict__ station_embedding,
    const float* __restrict__ raw_field_embed,
    const int* __restrict__ his_nodes,
    const int* __restrict__ now_nodes,
    const int* __restrict__ user_id,
    const float* __restrict__ user_emb_table,
    const float* __restrict__ station_emb_table,
    const float* __restrict__ proj_w,
    const float* __restrict__ proj_b,
    const float* __restrict__ theta,
    const float* __restrict__ alpha,
    const float* __restrict__ w_his1,
    const float* __restrict__ b_his1,
    const float* __restrict__ w_his2,
    const float* __restrict__ b_his2,
    const float* __restrict__ w_st,
    const float* __restrict__ b_st,
    const float* __restrict__ w_u,
    const float* __restrict__ b_u,
    float* __restrict__ ws,
    float* __restrict__ out)
{
    __shared__ float s_v[128];
    __shared__ float s_v2[64];
    __shared__ int   s_nodes[64];   // [0..31] now, [32..63] his
    __shared__ float s_vals[64];
    __shared__ float s_c, s_c2, s_uc;
    const int t = threadIdx.x;
    const int b = blockIdx.x;

    if (t < 128) {
        float acc = 0.f;
        for (int j = 0; j < D; ++j) acc += proj_w[t * D + j] * w_st[j];
        s_v[t] = acc;
        if (b == 0) ws[WS_V + t] = acc;
    } else if (t < 192) {
        int u = t - 128;
        float acc = 0.f;
        for (int j = 0; j < D; ++j) acc += w_his2[u * D + j] * w_st[j];
        s_v2[u] = acc;
    } else if (t == 192) {
        float acc = 0.f;
        for (int j = 0; j < D; ++j) acc += proj_b[j] * w_st[j];
        s_c = acc;
        if (b == 0) ws[WS_C] = acc;
    } else if (t == 193) {
        float acc = 0.f;
        for (int j = 0; j < D; ++j) acc += b_his2[j] * w_st[j];
        s_c2 = acc;
    } else if (t == 194) {
        int uid = user_id[b];
        float th = theta[uid];
        float acc = 0.f;
        for (int dd = 0; dd < D; ++dd)
            acc += ((1.f - th) * user_embedding[b * D + dd] +
                    th * user_emb_table[(size_t)uid * D + dd]) * w_u[dd];
        float uc = acc + b_u[0] + b_st[0];
        s_uc = uc;
        ws[WS_UC + b] = uc;
    }
    if (t < 64)
        s_nodes[t] = (t < K) ? now_nodes[b * K + t] : his_nodes[b * K + (t - K)];
    __syncthreads();

    const int w = t >> 6, lane = t & 63;
    // his contributions: wave w handles his rows j = w*8 .. w*8+7
    for (int r = 0; r < 8; ++r) {
        int j = w * 8 + r;               // 0..31
        int n = s_nodes[32 + j];
        float h1 = b_his1[lane];
        for (int dd = 0; dd < D; ++dd)
            h1 += raw_field_embed[(size_t)n * D + dd] * w_his1[dd * 64 + lane];
        float h1a = h1 > 0.f ? h1 : 0.01f * h1;   // jax leaky_relu default
        float contrib = h1a * s_v2[lane];
        for (int off = 32; off >= 1; off >>= 1)
            contrib += __shfl_down(contrib, off, 64);
        if (lane == 0) s_vals[32 + j] = alpha[n] * (contrib + s_c2);
    }
    // now contributions: wave w handles now rows j = w*8 .. w*8+7
    for (int r = 0; r < 8; ++r) {
        int j = w * 8 + r;
        int n = s_nodes[j];
        float p = station_embedding[(size_t)n * D + lane] * w_st[lane]
                + station_embedding[(size_t)n * D + 64 + lane] * w_st[64 + lane];
        for (int off = 32; off >= 1; off >>= 1)
            p += __shfl_down(p, off, 64);
        if (lane == 0) s_vals[j] = alpha[n] * p;
    }
    __syncthreads();

    if (t < 64) {
        int n = s_nodes[t];
        bool first = true;
        for (int i = 0; i < t; ++i)
            if (s_nodes[i] == n) { first = false; break; }
        if (first) {
            float sum = 0.f;
            for (int i = 0; i < 64; ++i)
                if (s_nodes[i] == n) sum += s_vals[i];
            float s = s_c;
            for (int dd = 0; dd < D; ++dd)
                s += station_emb_table[(size_t)n * D + dd] * s_v[dd];
            out[(size_t)b * NU + n] = (1.f - alpha[n]) * s + s_uc + sum;
        }
    }
}

// Streaming kernel: out[b,n] = set[n].v + c + uc[b] for all non-overridden
// entries; overridden (b,n) were already written by k_patch (disjoint sets).
__global__ __launch_bounds__(256) void k_main(
    const float* __restrict__ set,   // station_emb_table
    const int* __restrict__ his_nodes,
    const int* __restrict__ now_nodes,
    const float* __restrict__ ws,
    float* __restrict__ out)
{
    __shared__ float s_v[128];
    __shared__ float s_tile[64];
    __shared__ float s_uc[8];
    __shared__ float s_c;
    __shared__ unsigned char s_flag[8 * 64];
    const int t = threadIdx.x;
    if (t < 128) { s_v[t] = ws[WS_V + t]; ((int*)s_flag)[t] = 0; }
    if (t == 128) s_c = ws[WS_C];
    if (t >= 136 && t < 144) s_uc[t - 136] = ws[WS_UC + t - 136];
    __syncthreads();

    const int row0 = blockIdx.x * 64;
    // skip-flags from the raw node lists (t indexes all 256 (b,k) pairs)
    {
        int n0 = now_nodes[t];
        if ((n0 >> 6) == (int)blockIdx.x) s_flag[(t >> 5) * 64 + (n0 & 63)] = 1;
        int n1 = his_nodes[t];
        if ((n1 >> 6) == (int)blockIdx.x) s_flag[(t >> 5) * 64 + (n1 & 63)] = 1;
    }

    const int w    = t >> 6;
    const int lane = t & 63;
    const int half = lane >> 5;
    const int l32  = lane & 31;
    const float4 vv = ((const float4*)s_v)[l32];
    const float  c  = s_c;

    // wave reads rows R (lanes 0-31) and R+1 (lanes 32-63): 1024 B contiguous
    for (int i = 0; i < 8; ++i) {
        int r = i * 8 + w * 2 + half;
        int row = row0 + r;
        float acc = 0.f;
        if (row < NU) {
            float4 x = ((const float4*)(set + (size_t)row * D))[l32];
            acc = x.x * vv.x + x.y * vv.y + x.z * vv.z + x.w * vv.w;
        }
        for (int off = 16; off >= 1; off >>= 1)
            acc += __shfl_down(acc, off, 32);
        if (l32 == 0) s_tile[r] = acc + c;
    }
    __syncthreads();

    const int nl = t & 63;
    const int b0 = t >> 6;          // 0..3
    const int row = row0 + nl;
    if (row < NU) {
        float sv = s_tile[nl];
        if (!s_flag[b0 * 64 + nl])
            out[(size_t)b0 * NU + row] = sv + s_uc[b0];
        if (!s_flag[(b0 + 4) * 64 + nl])
            out[(size_t)(b0 + 4) * NU + row] = sv + s_uc[b0 + 4];
    }
}

extern "C" void kernel_launch(void* const* d_in, const int* in_sizes, int n_in,
                              void* d_out, int out_size, void* d_ws, size_t ws_size,
                              hipStream_t stream) {
    const float* user_embedding    = (const float*)d_in[0];
    const float* station_embedding = (const float*)d_in[1];
    const float* raw_field_embed   = (const float*)d_in[2];
    const int*   his_nodes         = (const int*)d_in[3];
    const int*   now_nodes         = (const int*)d_in[4];
    const int*   user_id           = (const int*)d_in[5];
    const float* user_emb_table    = (const float*)d_in[6];
    const float* station_emb_table = (const float*)d_in[7];
    const float* proj_w            = (const float*)d_in[8];
    const float* proj_b            = (const float*)d_in[9];
    const float* theta             = (const float*)d_in[10];
    const float* alpha             = (const float*)d_in[11];
    const float* w_his1            = (const float*)d_in[12];
    const float* b_his1            = (const float*)d_in[13];
    const float* w_his2            = (const float*)d_in[14];
    const float* b_his2            = (const float*)d_in[15];
    const float* w_st              = (const float*)d_in[16];
    const float* b_st              = (const float*)d_in[17];
    const float* w_u               = (const float*)d_in[18];
    const float* b_u               = (const float*)d_in[19];
    float* out = (float*)d_out;
    float* ws  = (float*)d_ws;

    hipLaunchKernelGGL(k_patch, dim3(B), dim3(256), 0, stream,
                       user_embedding, station_embedding, raw_field_embed,
                       his_nodes, now_nodes, user_id, user_emb_table,
                       station_emb_table, proj_w, proj_b, theta, alpha,
                       w_his1, b_his1, w_his2, b_his2,
                       w_st, b_st, w_u, b_u, ws, out);

    hipLaunchKernelGGL(k_main, dim3((NU + 63) / 64), dim3(256), 0, stream,
                       station_emb_table, his_nodes, now_nodes, ws, out);
}

// Round 3
// 166.311 us; speedup vs baseline: 1.2060x; 1.2060x over previous
//
#include <hip/hip_runtime.h>

#define NU 60082
#define NST 14695
#define D 128
#define B 8
#define K 32
#define NSTREAM ((NU + 63) / 64)   // 939 stream blocks, 64 rows each

// Single fused kernel. Blocks 0..B-1 handle the <=64 overridden entries of
// batch row b (scatter semantics, duplicate-accumulating, first-occurrence
// dedup). Blocks B.. handle 64 output rows each for all 8 batch rows,
// skipping overridden entries via a flag map. Write sets are disjoint, so
// no inter-block ordering is required.
__global__ __launch_bounds__(256) void k_fused(
    const float* __restrict__ user_embedding,
    const float* __restrict__ station_embedding,
    const float* __restrict__ raw_field_embed,
    const int* __restrict__ his_nodes,
    const int* __restrict__ now_nodes,
    const int* __restrict__ user_id,
    const float* __restrict__ user_emb_table,
    const float* __restrict__ station_emb_table,
    const float* __restrict__ proj_w,
    const float* __restrict__ proj_b,
    const float* __restrict__ theta,
    const float* __restrict__ alpha,
    const float* __restrict__ w_his1,
    const float* __restrict__ b_his1,
    const float* __restrict__ w_his2,
    const float* __restrict__ b_his2,
    const float* __restrict__ w_st,
    const float* __restrict__ b_st,
    const float* __restrict__ w_u,
    const float* __restrict__ b_u,
    float* __restrict__ out)
{
    const int t = threadIdx.x;

    if (blockIdx.x < B) {
        // ================= patch block for batch row b =================
        __shared__ float s_wst[128];
        __shared__ float s_v[128];        // proj_w @ w_st
        __shared__ float s_v2[64];        // w_his2 @ w_st
        __shared__ float s_rfe[32][128];  // gathered raw_field_embed rows
        __shared__ int   s_nodes[64];     // [0..31] now, [32..63] his
        __shared__ float s_alpha[64];
        __shared__ float s_vals[64];
        __shared__ float s_sn[64];
        __shared__ float s_c, s_c2, s_uc;
        const int b = blockIdx.x;

        // phase A: w_st -> LDS, node lists -> LDS
        if (t < 32) ((float4*)s_wst)[t] = ((const float4*)w_st)[t];
        if (t >= 64 && t < 128) {
            int j = t - 64;
            s_nodes[j] = (j < K) ? now_nodes[b * K + j] : his_nodes[b * K + (j - K)];
        }
        __syncthreads();

        // phase B: v, v2, c, c2 (float4, L2-friendly)
        if (t < 128) {
            float acc = 0.f;
            const float4* pr = (const float4*)(proj_w + t * D);
            #pragma unroll 8
            for (int j = 0; j < 32; ++j) {
                float4 x = pr[j];
                float4 wv = ((float4*)s_wst)[j];
                acc += x.x * wv.x + x.y * wv.y + x.z * wv.z + x.w * wv.w;
            }
            s_v[t] = acc;
        } else if (t < 192) {
            int u = t - 128;
            float acc = 0.f;
            const float4* pr = (const float4*)(w_his2 + u * D);
            #pragma unroll 8
            for (int j = 0; j < 32; ++j) {
                float4 x = pr[j];
                float4 wv = ((float4*)s_wst)[j];
                acc += x.x * wv.x + x.y * wv.y + x.z * wv.z + x.w * wv.w;
            }
            s_v2[u] = acc;
        } else if (t < 224) {
            int l = t - 192;
            float4 x = ((const float4*)proj_b)[l];
            float4 wv = ((float4*)s_wst)[l];
            float p = x.x * wv.x + x.y * wv.y + x.z * wv.z + x.w * wv.w;
            #pragma unroll
            for (int off = 16; off >= 1; off >>= 1) p += __shfl_down(p, off, 32);
            if (l == 0) s_c = p;
        } else {
            int l = t - 224;
            float4 x = ((const float4*)b_his2)[l];
            float4 wv = ((float4*)s_wst)[l];
            float p = x.x * wv.x + x.y * wv.y + x.z * wv.z + x.w * wv.w;
            #pragma unroll
            for (int off = 16; off >= 1; off >>= 1) p += __shfl_down(p, off, 32);
            if (l == 0) s_c2 = p;
        }
        // phase C: uc (32 lanes), alpha gather (nodes are post-sync valid)
        if (t < 32) {
            int uid = user_id[b];
            float th = theta[uid];
            float4 ue = ((const float4*)(user_embedding + b * D))[t];
            float4 ut = ((const float4*)(user_emb_table + (size_t)uid * D))[t];
            float4 wu = ((const float4*)w_u)[t];
            float p = ((1.f - th) * ue.x + th * ut.x) * wu.x
                    + ((1.f - th) * ue.y + th * ut.y) * wu.y
                    + ((1.f - th) * ue.z + th * ut.z) * wu.z
                    + ((1.f - th) * ue.w + th * ut.w) * wu.w;
            #pragma unroll
            for (int off = 16; off >= 1; off >>= 1) p += __shfl_down(p, off, 32);
            if (t == 0) s_uc = p + b_u[0] + b_st[0];
        }
        if (t >= 32 && t < 96) s_alpha[t - 32] = alpha[s_nodes[t - 32]];
        __syncthreads();

        // phase D: stage rfe rows (coalesced 8 threads/row)
        {
            int j = t >> 3, c8 = t & 7;
            int n = s_nodes[32 + j];
            const float4* src = (const float4*)(raw_field_embed + (size_t)n * D);
            #pragma unroll
            for (int i = 0; i < 4; ++i)
                ((float4*)s_rfe[j])[c8 + 8 * i] = src[c8 + 8 * i];
        }
        __syncthreads();

        // phase E: his-MLP. thread = (hidden unit u, wave w); wave w owns 8 rows.
        {
            const int u = t & 63, w = t >> 6;
            const float v2u = s_v2[u];
            const float bias = b_his1[u];
            float h1[8];
            #pragma unroll
            for (int j = 0; j < 8; ++j) h1[j] = bias;
            for (int dd = 0; dd < 128; dd += 8) {
                float wr[8];
                #pragma unroll
                for (int i = 0; i < 8; ++i) wr[i] = w_his1[(dd + i) * 64 + u];
                #pragma unroll
                for (int j = 0; j < 8; ++j) {
                    const float4* rf = (const float4*)&s_rfe[w * 8 + j][dd];
                    float4 a = rf[0], b4 = rf[1];
                    h1[j] += a.x * wr[0] + a.y * wr[1] + a.z * wr[2] + a.w * wr[3]
                           + b4.x * wr[4] + b4.y * wr[5] + b4.z * wr[6] + b4.w * wr[7];
                }
            }
            #pragma unroll
            for (int j = 0; j < 8; ++j) {
                float ha = h1[j] > 0.f ? h1[j] : 0.01f * h1[j];
                float val = ha * v2u;
                #pragma unroll
                for (int off = 32; off >= 1; off >>= 1) val += __shfl_down(val, off, 64);
                if (u == 0)
                    s_vals[32 + w * 8 + j] = s_alpha[32 + w * 8 + j] * (val + s_c2);
            }
        }
        // phase F: now contributions (coalesced gathers)
        {
            const int u = t & 63, w = t >> 6;
            #pragma unroll
            for (int r = 0; r < 8; ++r) {
                int j = w * 8 + r;
                int n = s_nodes[j];
                const float* se = station_embedding + (size_t)n * D;
                float p = se[u] * s_wst[u] + se[64 + u] * s_wst[64 + u];
                #pragma unroll
                for (int off = 32; off >= 1; off >>= 1) p += __shfl_down(p, off, 64);
                if (u == 0) s_vals[j] = s_alpha[j] * p;
            }
        }
        // phase G: s[n] = set[n].v + c, 4 lanes per node
        {
            int node = t >> 2, q = t & 3;
            const float4* sr = (const float4*)(station_emb_table + (size_t)s_nodes[node] * D);
            float p = 0.f;
            #pragma unroll
            for (int i = 0; i < 8; ++i) {
                float4 x = sr[q + 4 * i];
                float4 vv = ((float4*)s_v)[q + 4 * i];
                p += x.x * vv.x + x.y * vv.y + x.z * vv.z + x.w * vv.w;
            }
            p += __shfl_down(p, 2, 4);
            p += __shfl_down(p, 1, 4);
            if (q == 0) s_sn[node] = p + s_c;
        }
        __syncthreads();

        // phase H: dedup + write (duplicates accumulate, JAX .add semantics)
        if (t < 64) {
            int n = s_nodes[t];
            bool first = true;
            for (int i = 0; i < t; ++i)
                if (s_nodes[i] == n) { first = false; break; }
            if (first) {
                float sum = 0.f;
                for (int i = 0; i < 64; ++i)
                    if (s_nodes[i] == n) sum += s_vals[i];
                out[(size_t)b * NU + n] = (1.f - s_alpha[t]) * s_sn[t] + s_uc + sum;
            }
        }
    } else {
        // ================= stream block =================
        __shared__ float st_wst[128];
        __shared__ float st_v[128];
        __shared__ float st_tile[64];
        __shared__ float st_uc[8];
        __shared__ unsigned char st_flag[8 * 64];
        __shared__ float st_c;
        const int sb = blockIdx.x - B;
        const int row0 = sb * 64;

        // phase A: w_st -> LDS, zero flags
        if (t < 32) ((float4*)st_wst)[t] = ((const float4*)w_st)[t];
        if (t >= 128) ((int*)st_flag)[t - 128] = 0;
        __syncthreads();

        // phase B: v (t<128), c (wave 2 lower half)
        if (t < 128) {
            float acc = 0.f;
            const float4* pr = (const float4*)(proj_w + t * D);
            #pragma unroll 8
            for (int j = 0; j < 32; ++j) {
                float4 x = pr[j];
                float4 wv = ((float4*)st_wst)[j];
                acc += x.x * wv.x + x.y * wv.y + x.z * wv.z + x.w * wv.w;
            }
            st_v[t] = acc;
        } else if (t < 160) {
            int l = t - 128;
            float4 x = ((const float4*)proj_b)[l];
            float4 wv = ((float4*)st_wst)[l];
            float p = x.x * wv.x + x.y * wv.y + x.z * wv.z + x.w * wv.w;
            #pragma unroll
            for (int off = 16; off >= 1; off >>= 1) p += __shfl_down(p, off, 32);
            if (l == 0) st_c = p;
        }
        // phase C: skip-flags + uc[0..7] (32 lanes per user)
        {
            int n0 = now_nodes[t];
            if ((n0 >> 6) == sb) st_flag[(t >> 5) * 64 + (n0 & 63)] = 1;
            int n1 = his_nodes[t];
            if ((n1 >> 6) == sb) st_flag[(t >> 5) * 64 + (n1 & 63)] = 1;
        }
        {
            int u = t >> 5, l = t & 31;
            int uid = user_id[u];
            float th = theta[uid];
            float4 ue = ((const float4*)(user_embedding + u * D))[l];
            float4 ut = ((const float4*)(user_emb_table + (size_t)uid * D))[l];
            float4 wu = ((const float4*)w_u)[l];
            float p = ((1.f - th) * ue.x + th * ut.x) * wu.x
                    + ((1.f - th) * ue.y + th * ut.y) * wu.y
                    + ((1.f - th) * ue.z + th * ut.z) * wu.z
                    + ((1.f - th) * ue.w + th * ut.w) * wu.w;
            #pragma unroll
            for (int off = 16; off >= 1; off >>= 1) p += __shfl_down(p, off, 32);
            if (l == 0) st_uc[u] = p + b_u[0] + b_st[0];
        }
        __syncthreads();

        // stream 64 rows: wave reads rows R,R+1 (1 KiB contiguous)
        const int w    = t >> 6;
        const int lane = t & 63;
        const int half = lane >> 5;
        const int l32  = lane & 31;
        const float4 vv = ((const float4*)st_v)[l32];
        const float  c  = st_c;
        #pragma unroll
        for (int i = 0; i < 8; ++i) {
            int r = i * 8 + w * 2 + half;
            int row = row0 + r;
            float acc = 0.f;
            if (row < NU) {
                float4 x = ((const float4*)(station_emb_table + (size_t)row * D))[l32];
                acc = x.x * vv.x + x.y * vv.y + x.z * vv.z + x.w * vv.w;
            }
            #pragma unroll
            for (int off = 16; off >= 1; off >>= 1) acc += __shfl_down(acc, off, 32);
            if (l32 == 0) st_tile[r] = acc + c;
        }
        __syncthreads();

        const int nl = t & 63;
        const int b0 = t >> 6;   // 0..3
        const int row = row0 + nl;
        if (row < NU) {
            float sv = st_tile[nl];
            if (!st_flag[b0 * 64 + nl])
                out[(size_t)b0 * NU + row] = sv + st_uc[b0];
            if (!st_flag[(b0 + 4) * 64 + nl])
                out[(size_t)(b0 + 4) * NU + row] = sv + st_uc[b0 + 4];
        }
    }
}

extern "C" void kernel_launch(void* const* d_in, const int* in_sizes, int n_in,
                              void* d_out, int out_size, void* d_ws, size_t ws_size,
                              hipStream_t stream) {
    const float* user_embedding    = (const float*)d_in[0];
    const float* station_embedding = (const float*)d_in[1];
    const float* raw_field_embed   = (const float*)d_in[2];
    const int*   his_nodes         = (const int*)d_in[3];
    const int*   now_nodes         = (const int*)d_in[4];
    const int*   user_id           = (const int*)d_in[5];
    const float* user_emb_table    = (const float*)d_in[6];
    const float* station_emb_table = (const float*)d_in[7];
    const float* proj_w            = (const float*)d_in[8];
    const float* proj_b            = (const float*)d_in[9];
    const float* theta             = (const float*)d_in[10];
    const float* alpha             = (const float*)d_in[11];
    const float* w_his1            = (const float*)d_in[12];
    const float* b_his1            = (const float*)d_in[13];
    const float* w_his2            = (const float*)d_in[14];
    const float* b_his2            = (const float*)d_in[15];
    const float* w_st              = (const float*)d_in[16];
    const float* b_st              = (const float*)d_in[17];
    const float* w_u               = (const float*)d_in[18];
    const float* b_u               = (const float*)d_in[19];
    float* out = (float*)d_out;

    hipLaunchKernelGGL(k_fused, dim3(B + NSTREAM), dim3(256), 0, stream,
                       user_embedding, station_embedding, raw_field_embed,
                       his_nodes, now_nodes, user_id, user_emb_table,
                       station_emb_table, proj_w, proj_b, theta, alpha,
                       w_his1, b_his1, w_his2, b_his2,
                       w_st, b_st, w_u, b_u, out);
}

// Round 4
// 157.517 us; speedup vs baseline: 1.2733x; 1.0558x over previous
//
#include <hip/hip_runtime.h>

#define NU 60082
#define NST 14695
#define D 128
#define B 8
#define K 32
#define NBLK ((NU + 63) / 64)   // 939 blocks, 64 output rows each

// Single uniform kernel. Block sb owns output rows [sb*64, sb*64+64) for all
// 8 batch rows. Scatter slots (b,k) whose node lands in this block are
// collected into an LDS list; their overridden values are computed here
// (duplicates of (b,n) all land in the same block => exact JAX .add
// semantics with first-occurrence dedup). Non-flagged entries get the
// streaming value. Every out element is written exactly once.
__global__ __launch_bounds__(256) void k_fused(
    const float* __restrict__ user_embedding,
    const float* __restrict__ station_embedding,
    const float* __restrict__ raw_field_embed,
    const int* __restrict__ his_nodes,
    const int* __restrict__ now_nodes,
    const int* __restrict__ user_id,
    const float* __restrict__ user_emb_table,
    const float* __restrict__ station_emb_table,
    const float* __restrict__ proj_w,
    const float* __restrict__ proj_b,
    const float* __restrict__ theta,
    const float* __restrict__ alpha,
    const float* __restrict__ w_his1,
    const float* __restrict__ b_his1,
    const float* __restrict__ w_his2,
    const float* __restrict__ b_his2,
    const float* __restrict__ w_st,
    const float* __restrict__ b_st,
    const float* __restrict__ w_u,
    const float* __restrict__ b_u,
    float* __restrict__ out)
{
    __shared__ float s_wst[128];
    __shared__ float s_v[128];          // proj_w @ w_st
    __shared__ float s_v2[64];          // w_his2 @ w_st (only if his slot here)
    __shared__ float s_tile[64];        // s[n] for this block's rows
    __shared__ float s_uc[8];
    __shared__ unsigned char s_flag[8 * 64];
    __shared__ short s_lslot[512];      // flagged slots: now = t, his = 256+t
    __shared__ int   s_lnode[512];
    __shared__ float s_lval[512];
    __shared__ int   s_cnt, s_hcnt;
    __shared__ float s_c, s_c2;

    const int t  = threadIdx.x;
    const int sb = blockIdx.x;
    const int row0 = sb * 64;

    // ---- phase A: w_st -> LDS, zero flags/counters ----
    if (t < 32) ((float4*)s_wst)[t] = ((const float4*)w_st)[t];
    if (t >= 64 && t < 192) ((int*)s_flag)[t - 64] = 0;
    if (t == 192) s_cnt = 0;
    if (t == 193) s_hcnt = 0;
    __syncthreads();

    // ---- phase B: v = proj_w @ w_st (t<128), c (t 128..159), c2 (t 160..191)
    if (t < 128) {
        float acc = 0.f;
        const float4* pr = (const float4*)(proj_w + t * D);
        #pragma unroll 8
        for (int j = 0; j < 32; ++j) {
            float4 x = pr[j];
            float4 wv = ((float4*)s_wst)[j];
            acc += x.x * wv.x + x.y * wv.y + x.z * wv.z + x.w * wv.w;
        }
        s_v[t] = acc;
    } else if (t < 160) {
        int l = t - 128;
        float4 x = ((const float4*)proj_b)[l];
        float4 wv = ((float4*)s_wst)[l];
        float p = x.x * wv.x + x.y * wv.y + x.z * wv.z + x.w * wv.w;
        #pragma unroll
        for (int off = 16; off >= 1; off >>= 1) p += __shfl_down(p, off, 32);
        if (l == 0) s_c = p;
    } else if (t < 192) {
        int l = t - 160;
        float4 x = ((const float4*)b_his2)[l];
        float4 wv = ((float4*)s_wst)[l];
        float p = x.x * wv.x + x.y * wv.y + x.z * wv.z + x.w * wv.w;
        #pragma unroll
        for (int off = 16; off >= 1; off >>= 1) p += __shfl_down(p, off, 32);
        if (l == 0) s_c2 = p;
    }

    // ---- phase C: flags + compact slot list; uc[0..7] ----
    {
        int n0 = now_nodes[t];
        if ((n0 >> 6) == sb) {
            s_flag[(t >> 5) * 64 + (n0 & 63)] = 1;
            int i = atomicAdd(&s_cnt, 1);
            s_lslot[i] = (short)t;
            s_lnode[i] = n0;
        }
        int n1 = his_nodes[t];
        if ((n1 >> 6) == sb) {
            s_flag[(t >> 5) * 64 + (n1 & 63)] = 1;
            int i = atomicAdd(&s_cnt, 1);
            s_lslot[i] = (short)(256 + t);
            s_lnode[i] = n1;
            atomicAdd(&s_hcnt, 1);
        }
    }
    {
        int u = t >> 5, l = t & 31;
        int uid = user_id[u];
        float th = theta[uid];
        float4 ue = ((const float4*)(user_embedding + u * D))[l];
        float4 ut = ((const float4*)(user_emb_table + (size_t)uid * D))[l];
        float4 wu = ((const float4*)w_u)[l];
        float p = ((1.f - th) * ue.x + th * ut.x) * wu.x
                + ((1.f - th) * ue.y + th * ut.y) * wu.y
                + ((1.f - th) * ue.z + th * ut.z) * wu.z
                + ((1.f - th) * ue.w + th * ut.w) * wu.w;
        #pragma unroll
        for (int off = 16; off >= 1; off >>= 1) p += __shfl_down(p, off, 32);
        if (l == 0) s_uc[u] = p + b_u[0] + b_st[0];
    }
    __syncthreads();

    const int cnt  = s_cnt;
    const int hcnt = s_hcnt;

    // ---- phase D: stream 64 rows; wave reads rows R,R+1 (1 KiB contiguous)
    const int w    = t >> 6;
    const int lane = t & 63;
    const int half = lane >> 5;
    const int l32  = lane & 31;
    const float4 vv = ((const float4*)s_v)[l32];
    const float  c  = s_c;
    #pragma unroll
    for (int i = 0; i < 8; ++i) {
        int r = i * 8 + w * 2 + half;
        int row = row0 + r;
        float acc = 0.f;
        if (row < NU) {
            float4 x = ((const float4*)(station_emb_table + (size_t)row * D))[l32];
            acc = x.x * vv.x + x.y * vv.y + x.z * vv.z + x.w * vv.w;
        }
        #pragma unroll
        for (int off = 16; off >= 1; off >>= 1) acc += __shfl_down(acc, off, 32);
        if (l32 == 0) s_tile[r] = acc + c;
    }
    __syncthreads();

    // ---- write-out of non-flagged entries ----
    {
        const int nl = t & 63;
        const int b0 = t >> 6;   // 0..3
        const int row = row0 + nl;
        if (row < NU) {
            float sv = s_tile[nl];
            if (!s_flag[b0 * 64 + nl])
                out[(size_t)b0 * NU + row] = sv + s_uc[b0];
            if (!s_flag[(b0 + 4) * 64 + nl])
                out[(size_t)(b0 + 4) * NU + row] = sv + s_uc[b0 + 4];
        }
    }

    // ---- phase E: overridden entries (block-uniform branch) ----
    if (cnt > 0) {
        if (hcnt > 0) {
            // v2 = w_his2 @ w_st, 4 threads per row (coalesced float4)
            int row = t >> 2, q = t & 3;
            const float4* wr = (const float4*)(w_his2 + row * D);
            float p = 0.f;
            #pragma unroll
            for (int i = 0; i < 8; ++i) {
                float4 x = wr[q + 4 * i];
                float4 wv = ((float4*)s_wst)[q + 4 * i];
                p += x.x * wv.x + x.y * wv.y + x.z * wv.z + x.w * wv.w;
            }
            p += __shfl_down(p, 2, 4);
            p += __shfl_down(p, 1, 4);
            if (q == 0) s_v2[row] = p;
        }
        __syncthreads();

        // one wave per list entry (stride 4)
        for (int i = w; i < cnt; i += 4) {
            int slot = s_lslot[i];
            int n = s_lnode[i];
            float val;
            if (slot < 256) {
                // now: alpha[n] * (station_embedding[n] . w_st)
                const float* se = station_embedding + (size_t)n * D;
                float p = se[lane] * s_wst[lane] + se[64 + lane] * s_wst[64 + lane];
                #pragma unroll
                for (int off = 32; off >= 1; off >>= 1) p += __shfl_down(p, off, 64);
                val = alpha[n] * p;
            } else {
                // his: alpha[n] * (MLP(rfe[n]) . w_st); lane = hidden unit
                const float4* rf = (const float4*)(raw_field_embed + (size_t)n * D);
                float h1 = b_his1[lane];
                #pragma unroll 8
                for (int j = 0; j < 32; ++j) {
                    float4 r = rf[j];   // broadcast load
                    h1 += r.x * w_his1[(4 * j + 0) * 64 + lane]
                        + r.y * w_his1[(4 * j + 1) * 64 + lane]
                        + r.z * w_his1[(4 * j + 2) * 64 + lane]
                        + r.w * w_his1[(4 * j + 3) * 64 + lane];
                }
                float ha = h1 > 0.f ? h1 : 0.01f * h1;   // jax leaky_relu default
                float p = ha * s_v2[lane];
                #pragma unroll
                for (int off = 32; off >= 1; off >>= 1) p += __shfl_down(p, off, 64);
                val = alpha[n] * (p + s_c2);
            }
            if (lane == 0) s_lval[i] = val;
        }
        __syncthreads();

        // dedup + write: first occurrence of (b,n) sums all matching slots
        if (t < cnt) {
            int n = s_lnode[t];
            int b = (s_lslot[t] & 255) >> 5;
            bool first = true;
            for (int i = 0; i < t; ++i)
                if (s_lnode[i] == n && ((s_lslot[i] & 255) >> 5) == b) { first = false; break; }
            if (first) {
                float sum = 0.f;
                for (int i = 0; i < cnt; ++i)
                    if (s_lnode[i] == n && ((s_lslot[i] & 255) >> 5) == b) sum += s_lval[i];
                out[(size_t)b * NU + n] = (1.f - alpha[n]) * s_tile[n - row0] + s_uc[b] + sum;
            }
        }
    }
}

extern "C" void kernel_launch(void* const* d_in, const int* in_sizes, int n_in,
                              void* d_out, int out_size, void* d_ws, size_t ws_size,
                              hipStream_t stream) {
    const float* user_embedding    = (const float*)d_in[0];
    const float* station_embedding = (const float*)d_in[1];
    const float* raw_field_embed   = (const float*)d_in[2];
    const int*   his_nodes         = (const int*)d_in[3];
    const int*   now_nodes         = (const int*)d_in[4];
    const int*   user_id           = (const int*)d_in[5];
    const float* user_emb_table    = (const float*)d_in[6];
    const float* station_emb_table = (const float*)d_in[7];
    const float* proj_w            = (const float*)d_in[8];
    const float* proj_b            = (const float*)d_in[9];
    const float* theta             = (const float*)d_in[10];
    const float* alpha             = (const float*)d_in[11];
    const float* w_his1            = (const float*)d_in[12];
    const float* b_his1            = (const float*)d_in[13];
    const float* w_his2            = (const float*)d_in[14];
    const float* b_his2            = (const float*)d_in[15];
    const float* w_st              = (const float*)d_in[16];
    const float* b_st              = (const float*)d_in[17];
    const float* w_u               = (const float*)d_in[18];
    const float* b_u               = (const float*)d_in[19];
    float* out = (float*)d_out;

    hipLaunchKernelGGL(k_fused, dim3(NBLK), dim3(256), 0, stream,
                       user_embedding, station_embedding, raw_field_embed,
                       his_nodes, now_nodes, user_id, user_emb_table,
                       station_emb_table, proj_w, proj_b, theta, alpha,
                       w_his1, b_his1, w_his2, b_his2,
                       w_st, b_st, w_u, b_u, out);
}

// Round 5
// 156.860 us; speedup vs baseline: 1.2786x; 1.0042x over previous
//
#include <hip/hip_runtime.h>

#define NU 60082
#define NST 14695
#define D 128
#define B 8
#define K 32
#define NBLK ((NU + 63) / 64)   // 939 blocks, 64 output rows each

// Single uniform kernel. Block sb owns output rows [sb*64, sb*64+64) for all
// 8 batch rows. Station-row loads are issued BEFORE the v-compute (they are
// independent) so HBM streaming overlaps the proj_w dot. Scatter slots (b,k)
// whose node lands in this block are collected into an LDS list and computed
// here (all duplicates of (b,n) land in the same block => exact JAX .add
// semantics). Every out element is written exactly once.
__global__ __launch_bounds__(256) void k_fused(
    const float* __restrict__ user_embedding,
    const float* __restrict__ station_embedding,
    const float* __restrict__ raw_field_embed,
    const int* __restrict__ his_nodes,
    const int* __restrict__ now_nodes,
    const int* __restrict__ user_id,
    const float* __restrict__ user_emb_table,
    const float* __restrict__ station_emb_table,
    const float* __restrict__ proj_w,
    const float* __restrict__ proj_b,
    const float* __restrict__ theta,
    const float* __restrict__ alpha,
    const float* __restrict__ w_his1,
    const float* __restrict__ b_his1,
    const float* __restrict__ w_his2,
    const float* __restrict__ b_his2,
    const float* __restrict__ w_st,
    const float* __restrict__ b_st,
    const float* __restrict__ w_u,
    const float* __restrict__ b_u,
    float* __restrict__ out)
{
    __shared__ float s_wst[128];
    __shared__ float s_v[128];          // proj_w @ w_st
    __shared__ float s_v2[64];          // w_his2 @ w_st (only if his slot here)
    __shared__ float s_tile[64];        // s[n] for this block's rows
    __shared__ float s_uc[8];
    __shared__ unsigned char s_flag[8 * 64];
    __shared__ short s_lslot[512];      // flagged slots: now = t, his = 256+t
    __shared__ int   s_lnode[512];
    __shared__ float s_lval[512];
    __shared__ int   s_cnt, s_hcnt;
    __shared__ float s_c, s_c2;

    const int t  = threadIdx.x;
    const int sb = blockIdx.x;
    const int row0 = sb * 64;

    const int w    = t >> 6;
    const int lane = t & 63;
    const int half = lane >> 5;
    const int l32  = lane & 31;

    // ---- phase A: w_st -> LDS, zero flags/counters ----
    if (t < 32) ((float4*)s_wst)[t] = ((const float4*)w_st)[t];
    if (t >= 64 && t < 192) ((int*)s_flag)[t - 64] = 0;
    if (t == 192) s_cnt = 0;
    if (t == 193) s_hcnt = 0;

    // ---- phase A': issue the 8 station-row loads NOW (independent of v) ----
    // wave reads rows R,R+1 per iter (1 KiB contiguous); results land while
    // phase B computes.
    float4 xr[8];
    #pragma unroll
    for (int i = 0; i < 8; ++i) {
        int r = i * 8 + w * 2 + half;
        int row = row0 + r;
        if (row < NU)
            xr[i] = ((const float4*)(station_emb_table + (size_t)row * D))[l32];
        else
            xr[i] = make_float4(0.f, 0.f, 0.f, 0.f);
    }
    __syncthreads();   // s_wst visible (loads above don't touch LDS)

    // ---- phase B: v = proj_w @ w_st (t<128), c (t 128..159), c2 (t 160..191)
    if (t < 128) {
        float acc = 0.f;
        const float4* pr = (const float4*)(proj_w + t * D);
        #pragma unroll 8
        for (int j = 0; j < 32; ++j) {
            float4 x = pr[j];
            float4 wv = ((float4*)s_wst)[j];
            acc += x.x * wv.x + x.y * wv.y + x.z * wv.z + x.w * wv.w;
        }
        s_v[t] = acc;
    } else if (t < 160) {
        int l = t - 128;
        float4 x = ((const float4*)proj_b)[l];
        float4 wv = ((float4*)s_wst)[l];
        float p = x.x * wv.x + x.y * wv.y + x.z * wv.z + x.w * wv.w;
        #pragma unroll
        for (int off = 16; off >= 1; off >>= 1) p += __shfl_down(p, off, 32);
        if (l == 0) s_c = p;
    } else if (t < 192) {
        int l = t - 160;
        float4 x = ((const float4*)b_his2)[l];
        float4 wv = ((float4*)s_wst)[l];
        float p = x.x * wv.x + x.y * wv.y + x.z * wv.z + x.w * wv.w;
        #pragma unroll
        for (int off = 16; off >= 1; off >>= 1) p += __shfl_down(p, off, 32);
        if (l == 0) s_c2 = p;
    }

    // ---- phase C: flags + compact slot list; uc[0..7] ----
    {
        int n0 = now_nodes[t];
        if ((n0 >> 6) == sb) {
            s_flag[(t >> 5) * 64 + (n0 & 63)] = 1;
            int i = atomicAdd(&s_cnt, 1);
            s_lslot[i] = (short)t;
            s_lnode[i] = n0;
        }
        int n1 = his_nodes[t];
        if ((n1 >> 6) == sb) {
            s_flag[(t >> 5) * 64 + (n1 & 63)] = 1;
            int i = atomicAdd(&s_cnt, 1);
            s_lslot[i] = (short)(256 + t);
            s_lnode[i] = n1;
            atomicAdd(&s_hcnt, 1);
        }
    }
    {
        int u = t >> 5, l = t & 31;
        int uid = user_id[u];
        float th = theta[uid];
        float4 ue = ((const float4*)(user_embedding + u * D))[l];
        float4 ut = ((const float4*)(user_emb_table + (size_t)uid * D))[l];
        float4 wu = ((const float4*)w_u)[l];
        float p = ((1.f - th) * ue.x + th * ut.x) * wu.x
                + ((1.f - th) * ue.y + th * ut.y) * wu.y
                + ((1.f - th) * ue.z + th * ut.z) * wu.z
                + ((1.f - th) * ue.w + th * ut.w) * wu.w;
        #pragma unroll
        for (int off = 16; off >= 1; off >>= 1) p += __shfl_down(p, off, 32);
        if (l == 0) s_uc[u] = p + b_u[0] + b_st[0];
    }
    __syncthreads();

    const int cnt  = s_cnt;
    const int hcnt = s_hcnt;

    // ---- phase D: dot products from the prefetched registers ----
    const float4 vv = ((const float4*)s_v)[l32];
    const float  c  = s_c;
    #pragma unroll
    for (int i = 0; i < 8; ++i) {
        int r = i * 8 + w * 2 + half;
        float acc = xr[i].x * vv.x + xr[i].y * vv.y + xr[i].z * vv.z + xr[i].w * vv.w;
        #pragma unroll
        for (int off = 16; off >= 1; off >>= 1) acc += __shfl_down(acc, off, 32);
        if (l32 == 0) s_tile[r] = acc + c;
    }
    __syncthreads();

    // ---- write-out of non-flagged entries ----
    {
        const int nl = t & 63;
        const int b0 = t >> 6;   // 0..3
        const int row = row0 + nl;
        if (row < NU) {
            float sv = s_tile[nl];
            if (!s_flag[b0 * 64 + nl])
                out[(size_t)b0 * NU + row] = sv + s_uc[b0];
            if (!s_flag[(b0 + 4) * 64 + nl])
                out[(size_t)(b0 + 4) * NU + row] = sv + s_uc[b0 + 4];
        }
    }

    // ---- phase E: overridden entries (block-uniform branch) ----
    if (cnt > 0) {
        if (hcnt > 0) {
            // v2 = w_his2 @ w_st, 4 threads per row (coalesced float4)
            int row = t >> 2, q = t & 3;
            const float4* wr = (const float4*)(w_his2 + row * D);
            float p = 0.f;
            #pragma unroll
            for (int i = 0; i < 8; ++i) {
                float4 x = wr[q + 4 * i];
                float4 wv = ((float4*)s_wst)[q + 4 * i];
                p += x.x * wv.x + x.y * wv.y + x.z * wv.z + x.w * wv.w;
            }
            p += __shfl_down(p, 2, 4);
            p += __shfl_down(p, 1, 4);
            if (q == 0) s_v2[row] = p;
        }
        __syncthreads();

        // one wave per list entry (stride 4)
        for (int i = w; i < cnt; i += 4) {
            int slot = s_lslot[i];
            int n = s_lnode[i];
            float val;
            if (slot < 256) {
                // now: alpha[n] * (station_embedding[n] . w_st)
                const float* se = station_embedding + (size_t)n * D;
                float p = se[lane] * s_wst[lane] + se[64 + lane] * s_wst[64 + lane];
                #pragma unroll
                for (int off = 32; off >= 1; off >>= 1) p += __shfl_down(p, off, 64);
                val = alpha[n] * p;
            } else {
                // his: alpha[n] * (MLP(rfe[n]) . w_st); lane = hidden unit
                const float4* rf = (const float4*)(raw_field_embed + (size_t)n * D);
                float h1 = b_his1[lane];
                #pragma unroll 8
                for (int j = 0; j < 32; ++j) {
                    float4 r = rf[j];   // broadcast load
                    h1 += r.x * w_his1[(4 * j + 0) * 64 + lane]
                        + r.y * w_his1[(4 * j + 1) * 64 + lane]
                        + r.z * w_his1[(4 * j + 2) * 64 + lane]
                        + r.w * w_his1[(4 * j + 3) * 64 + lane];
                }
                float ha = h1 > 0.f ? h1 : 0.01f * h1;   // jax leaky_relu default
                float p = ha * s_v2[lane];
                #pragma unroll
                for (int off = 32; off >= 1; off >>= 1) p += __shfl_down(p, off, 64);
                val = alpha[n] * (p + s_c2);
            }
            if (lane == 0) s_lval[i] = val;
        }
        __syncthreads();

        // dedup + write: first occurrence of (b,n) sums all matching slots
        if (t < cnt) {
            int n = s_lnode[t];
            int b = (s_lslot[t] & 255) >> 5;
            bool first = true;
            for (int i = 0; i < t; ++i)
                if (s_lnode[i] == n && ((s_lslot[i] & 255) >> 5) == b) { first = false; break; }
            if (first) {
                float sum = 0.f;
                for (int i = 0; i < cnt; ++i)
                    if (s_lnode[i] == n && ((s_lslot[i] & 255) >> 5) == b) sum += s_lval[i];
                out[(size_t)b * NU + n] = (1.f - alpha[n]) * s_tile[n - row0] + s_uc[b] + sum;
            }
        }
    }
}

extern "C" void kernel_launch(void* const* d_in, const int* in_sizes, int n_in,
                              void* d_out, int out_size, void* d_ws, size_t ws_size,
                              hipStream_t stream) {
    const float* user_embedding    = (const float*)d_in[0];
    const float* station_embedding = (const float*)d_in[1];
    const float* raw_field_embed   = (const float*)d_in[2];
    const int*   his_nodes         = (const int*)d_in[3];
    const int*   now_nodes         = (const int*)d_in[4];
    const int*   user_id           = (const int*)d_in[5];
    const float* user_emb_table    = (const float*)d_in[6];
    const float* station_emb_table = (const float*)d_in[7];
    const float* proj_w            = (const float*)d_in[8];
    const float* proj_b            = (const float*)d_in[9];
    const float* theta             = (const float*)d_in[10];
    const float* alpha             = (const float*)d_in[11];
    const float* w_his1            = (const float*)d_in[12];
    const float* b_his1            = (const float*)d_in[13];
    const float* w_his2            = (const float*)d_in[14];
    const float* b_his2            = (const float*)d_in[15];
    const float* w_st              = (const float*)d_in[16];
    const float* b_st              = (const float*)d_in[17];
    const float* w_u               = (const float*)d_in[18];
    const float* b_u               = (const float*)d_in[19];
    float* out = (float*)d_out;

    hipLaunchKernelGGL(k_fused, dim3(NBLK), dim3(256), 0, stream,
                       user_embedding, station_embedding, raw_field_embed,
                       his_nodes, now_nodes, user_id, user_emb_table,
                       station_emb_table, proj_w, proj_b, theta, alpha,
                       w_his1, b_his1, w_his2, b_his2,
                       w_st, b_st, w_u, b_u, out);
}